// Round 4
// baseline (2888.658 us; speedup 1.0000x reference)
//
#include <hip/hip_runtime.h>
#include <math.h>

#define THREADS 256

// ---------------------------------------------------------------------------
__global__ void zero_kernel(float* __restrict__ p, int n) {
    int i = blockIdx.x * blockDim.x + threadIdx.x;
    if (i < n) p[i] = 0.f;
}

// deg[row] += ew  (self-loops excluded). edge_index is int32 (harness contract).
__global__ void deg_kernel(const int* __restrict__ row,
                           const int* __restrict__ col,
                           const float* __restrict__ ew,
                           float* __restrict__ deg, int E) {
    int e = blockIdx.x * blockDim.x + threadIdx.x;
    if (e >= E) return;
    int r = row[e];
    int c = col[e];
    float w = ew[e];
    if (r != c && w != 0.f) atomicAdd(&deg[r], w);
}

// ---------------------------------------------------------------------------
// Per-node init: deg -> dis (in place), Tx0 = x[:, :2], zero first prop accum,
// outacc = Tx0 @ W_cheb[0].
__global__ void init_kernel(const float* __restrict__ x,
                            float* __restrict__ deg,        // becomes dis
                            float2* __restrict__ tx0,
                            float2* __restrict__ raw1,      // zeroed
                            float2* __restrict__ outacc,
                            const float* __restrict__ Wc,
                            int N) {
    int i = blockIdx.x * blockDim.x + threadIdx.x;
    if (i >= N) return;
    float d = deg[i];
    deg[i] = (d > 0.f) ? rsqrtf(d) : 0.f;
    float x0 = x[3 * i + 0];
    float x1 = x[3 * i + 1];
    tx0[i]  = make_float2(x0, x1);
    raw1[i] = make_float2(0.f, 0.f);
    outacc[i] = make_float2(x0 * Wc[0] + x1 * Wc[2],
                            x0 * Wc[1] + x1 * Wc[3]);
}

// ---------------------------------------------------------------------------
// prop: o[col] += (-dis[row]*ew*dis[col]) * h[row]   (2-wide; dis L2-resident)
__global__ void prop_kernel(const int* __restrict__ row,
                            const int* __restrict__ col,
                            const float* __restrict__ ew,
                            const float* __restrict__ dis,
                            const float2* __restrict__ h,
                            float2* __restrict__ o,
                            int E) {
    int e = blockIdx.x * blockDim.x + threadIdx.x;
    if (e >= E) return;
    int r = row[e];
    int c = col[e];
    if (r == c) return;
    float w = -dis[r] * ew[e] * dis[c];
    if (w == 0.f) return;
    float2 hv = h[r];
    atomicAdd(&o[c].x, w * hv.x);
    atomicAdd(&o[c].y, w * hv.y);
}

// ---------------------------------------------------------------------------
// Chebyshev node step: v = (tx0 ? 2*raw - tx0 : raw); raw = v;
// outacc += v @ W_cheb[k]; optionally zero next accumulator buffer.
__global__ void cheb_node_kernel(float2* __restrict__ raw,
                                 const float2* __restrict__ tx0,
                                 float2* __restrict__ zbuf,
                                 float2* __restrict__ outacc,
                                 const float* __restrict__ Wc,
                                 int k, int N) {
    int i = blockIdx.x * blockDim.x + threadIdx.x;
    if (i >= N) return;
    float2 v = raw[i];
    if (tx0) {
        float2 t = tx0[i];
        v.x = 2.f * v.x - t.x;
        v.y = 2.f * v.y - t.y;
        raw[i] = v;
    }
    float2 o = outacc[i];
    o.x += v.x * Wc[4 * k + 0] + v.y * Wc[4 * k + 2];
    o.y += v.x * Wc[4 * k + 1] + v.y * Wc[4 * k + 3];
    outacc[i] = o;
    if (zbuf) zbuf[i] = make_float2(0.f, 0.f);
}

// ---------------------------------------------------------------------------
// u = x_turn*W0 + relu(out + cb)@W[1:3] + b; per-block max -> partials
__global__ void u_max_kernel(const float* __restrict__ x,
                             const float2* __restrict__ outacc,
                             const float* __restrict__ cb,
                             const float* __restrict__ W,
                             const float* __restrict__ b,
                             float* __restrict__ U,
                             float* __restrict__ partmax,
                             int N) {
    int i = blockIdx.x * blockDim.x + threadIdx.x;
    float u = -INFINITY;
    if (i < N) {
        float2 o = outacc[i];
        float h0 = fmaxf(o.x + cb[0], 0.f);
        float h1 = fmaxf(o.y + cb[1], 0.f);
        u = x[3 * i + 2] * W[0] + h0 * W[1] + h1 * W[2] + b[0];
        U[i] = u;
    }
    for (int off = 32; off > 0; off >>= 1) u = fmaxf(u, __shfl_down(u, off));
    __shared__ float s[THREADS / 64];
    if ((threadIdx.x & 63) == 0) s[threadIdx.x >> 6] = u;
    __syncthreads();
    if (threadIdx.x == 0) {
        float m = s[0];
        for (int w = 1; w < THREADS / 64; ++w) m = fmaxf(m, s[w]);
        partmax[blockIdx.x] = m;
    }
}

__global__ void reduce_max_kernel(const float* __restrict__ part, int n,
                                  float* __restrict__ dst) {
    float m = -INFINITY;
    for (int i = threadIdx.x; i < n; i += blockDim.x) m = fmaxf(m, part[i]);
    for (int off = 32; off > 0; off >>= 1) m = fmaxf(m, __shfl_down(m, off));
    __shared__ float s[16];
    int wid = threadIdx.x >> 6;
    if ((threadIdx.x & 63) == 0) s[wid] = m;
    __syncthreads();
    if (threadIdx.x == 0) {
        float r = s[0];
        int nw = blockDim.x >> 6;
        for (int w = 1; w < nw; ++w) r = fmaxf(r, s[w]);
        dst[0] = r;
    }
}

__global__ void exp_sum_kernel(float* __restrict__ U,
                               const float* __restrict__ gmax,
                               float* __restrict__ partsum, int N) {
    int i = blockIdx.x * blockDim.x + threadIdx.x;
    float e = 0.f;
    float m = gmax[0];
    if (i < N) {
        e = expf(U[i] - m);
        U[i] = e;
    }
    for (int off = 32; off > 0; off >>= 1) e += __shfl_down(e, off);
    __shared__ float s[THREADS / 64];
    if ((threadIdx.x & 63) == 0) s[threadIdx.x >> 6] = e;
    __syncthreads();
    if (threadIdx.x == 0) {
        float t = s[0];
        for (int w = 1; w < THREADS / 64; ++w) t += s[w];
        partsum[blockIdx.x] = t;
    }
}

__global__ void reduce_sum_kernel(const float* __restrict__ part, int n,
                                  float* __restrict__ dst) {
    float m = 0.f;
    for (int i = threadIdx.x; i < n; i += blockDim.x) m += part[i];
    for (int off = 32; off > 0; off >>= 1) m += __shfl_down(m, off);
    __shared__ float s[16];
    int wid = threadIdx.x >> 6;
    if ((threadIdx.x & 63) == 0) s[wid] = m;
    __syncthreads();
    if (threadIdx.x == 0) {
        float r = s[0];
        int nw = blockDim.x >> 6;
        for (int w = 1; w < nw; ++w) r += s[w];
        dst[0] = 1.f / r;
    }
}

__global__ void scale_kernel(const float* __restrict__ U,
                             const float* __restrict__ inv,
                             float* __restrict__ out, int N) {
    int i = blockIdx.x * blockDim.x + threadIdx.x;
    if (i < N) out[i] = U[i] * inv[0];
}

// ---------------------------------------------------------------------------
extern "C" void kernel_launch(void* const* d_in, const int* in_sizes, int n_in,
                              void* d_out, int out_size, void* d_ws, size_t ws_size,
                              hipStream_t stream) {
    (void)n_in; (void)out_size; (void)ws_size;
    const float* x    = (const float*)d_in[0];
    const int*   eidx = (const int*)d_in[1];     // int32 per harness contract!
    const float* ew   = (const float*)d_in[2];
    const float* Wc   = (const float*)d_in[3];
    const float* cb   = (const float*)d_in[4];
    const float* W    = (const float*)d_in[5];
    const float* b    = (const float*)d_in[6];
    float*       out  = (float*)d_out;

    const int N = in_sizes[0] / 3;
    const int E = in_sizes[2];
    const int K = in_sizes[3] / 4;
    const int* row = eidx;
    const int* col = eidx + E;

    char* ws = (char*)d_ws;
    size_t off = 0;
    auto take = [&](size_t bytes) -> void* {
        void* p = ws + off;
        off = (off + bytes + 255) & ~(size_t)255;
        return p;
    };

    float*  deg    = (float*)take((size_t)N * 4);   // becomes dis after init
    float2* A      = (float2*)take((size_t)N * 8);
    float2* B      = (float2*)take((size_t)N * 8);
    float2* C      = (float2*)take((size_t)N * 8);
    float2* outacc = (float2*)take((size_t)N * 8);
    float*  U      = (float*)take((size_t)N * 4);
    float*  part   = (float*)take(8192 * 4);
    float*  scal   = (float*)take(64 * 4);

    const int eb = (E + THREADS - 1) / THREADS;
    const int nb = (N + THREADS - 1) / THREADS;

    zero_kernel<<<nb, THREADS, 0, stream>>>(deg, N);
    deg_kernel<<<eb, THREADS, 0, stream>>>(row, col, ew, deg, E);
    init_kernel<<<nb, THREADS, 0, stream>>>(x, deg, A, B, outacc, Wc, N);
    const float* dis = deg;

    // k = 1
    prop_kernel<<<eb, THREADS, 0, stream>>>(row, col, ew, dis, A, B, E);
    cheb_node_kernel<<<nb, THREADS, 0, stream>>>(B, (const float2*)nullptr, C, outacc, Wc, 1, N);

    float2 *t0 = A, *t1 = B, *fr = C;
    for (int k = 2; k < K; ++k) {
        prop_kernel<<<eb, THREADS, 0, stream>>>(row, col, ew, dis, t1, fr, E);
        cheb_node_kernel<<<nb, THREADS, 0, stream>>>(fr, t0, (k + 1 < K) ? t0 : nullptr,
                                                     outacc, Wc, k, N);
        float2* n0 = t1; float2* n1 = fr; float2* nf = t0;
        t0 = n0; t1 = n1; fr = nf;
    }

    u_max_kernel<<<nb, THREADS, 0, stream>>>(x, outacc, cb, W, b, U, part, N);
    reduce_max_kernel<<<1, 1024, 0, stream>>>(part, nb, scal);
    exp_sum_kernel<<<nb, THREADS, 0, stream>>>(U, scal, part, N);
    reduce_sum_kernel<<<1, 1024, 0, stream>>>(part, nb, scal + 1);
    scale_kernel<<<nb, THREADS, 0, stream>>>(U, scal + 1, out, N);
}

// Round 5
// 1049.103 us; speedup vs baseline: 2.7535x; 2.7535x over previous
//
#include <hip/hip_runtime.h>
#include <math.h>

#define THREADS 256

// ---------------------------------------------------------------------------
__global__ void zero2_kernel(float* __restrict__ deg, int* __restrict__ cnt, int N) {
    int i = blockIdx.x * blockDim.x + threadIdx.x;
    if (i < N) { deg[i] = 0.f; cnt[i] = 0; }
}

__global__ void zerof2_kernel(float2* __restrict__ p, int N) {
    int i = blockIdx.x * blockDim.x + threadIdx.x;
    if (i < N) p[i] = make_float2(0.f, 0.f);
}

// One edge pass: weighted out-degree (over row) + incoming-edge count (over col).
__global__ void deg_cnt_kernel(const int* __restrict__ row,
                               const int* __restrict__ col,
                               const float* __restrict__ ew,
                               float* __restrict__ deg,
                               int* __restrict__ cnt, int E) {
    int e = blockIdx.x * blockDim.x + threadIdx.x;
    if (e >= E) return;
    int r = row[e];
    int c = col[e];
    if (r == c) return;
    float w = ew[e];
    if (w != 0.f) atomicAdd(&deg[r], w);
    atomicAdd(&cnt[c], 1);
}

// ---------------------------------------------------------------------------
// Per-node init: deg -> dis (in place), Tx0 = x[:, :2], outacc = Tx0 @ Wc[0].
__global__ void init_kernel(const float* __restrict__ x,
                            float* __restrict__ deg,        // becomes dis
                            float2* __restrict__ tx0,
                            float2* __restrict__ outacc,
                            const float* __restrict__ Wc,
                            int N) {
    int i = blockIdx.x * blockDim.x + threadIdx.x;
    if (i >= N) return;
    float d = deg[i];
    deg[i] = (d > 0.f) ? rsqrtf(d) : 0.f;
    float x0 = x[3 * i + 0];
    float x1 = x[3 * i + 1];
    tx0[i] = make_float2(x0, x1);
    outacc[i] = make_float2(x0 * Wc[0] + x1 * Wc[2],
                            x0 * Wc[1] + x1 * Wc[3]);
}

// ---------------------------------------------------------------------------
// Prefix scan of cnt[N] -> exclusive offsets rowstart[0..N].
__global__ void scan1_kernel(const int* __restrict__ cnt,
                             int* __restrict__ rowstart,
                             int* __restrict__ bsum, int N) {
    __shared__ int s[256];
    int t = threadIdx.x;
    int i = blockIdx.x * 256 + t;
    int v = (i < N) ? cnt[i] : 0;
    s[t] = v;
    __syncthreads();
    for (int d = 1; d < 256; d <<= 1) {
        int xv = (t >= d) ? s[t - d] : 0;
        __syncthreads();
        s[t] += xv;
        __syncthreads();
    }
    if (i < N) rowstart[i] = s[t] - v;           // block-local exclusive
    if (t == 255) bsum[blockIdx.x] = s[255];
}

__global__ void scan2_kernel(const int* __restrict__ bsum,
                             int* __restrict__ boff, int nb) {
    __shared__ int s[512];
    int t = threadIdx.x;
    int v = (t < nb) ? bsum[t] : 0;
    s[t] = v;
    __syncthreads();
    for (int d = 1; d < 512; d <<= 1) {
        int xv = (t >= d) ? s[t - d] : 0;
        __syncthreads();
        s[t] += xv;
        __syncthreads();
    }
    if (t < nb) boff[t] = s[t] - v;              // exclusive block offsets
    if (t == nb - 1) boff[nb] = s[t];            // grand total
}

__global__ void scan3_kernel(int* __restrict__ rowstart,
                             const int* __restrict__ boff,
                             int* __restrict__ cur, int N, int nb) {
    int i = blockIdx.x * blockDim.x + threadIdx.x;
    if (i < N) {
        int v = rowstart[i] + boff[i >> 8];
        rowstart[i] = v;
        cur[i] = v;
    } else if (i == N) {
        rowstart[N] = boff[nb];
    }
}

// ---------------------------------------------------------------------------
// Scatter edges into col-sorted order with precomputed norm, packed 8B records.
__global__ void scatter_kernel(const int* __restrict__ row,
                               const int* __restrict__ col,
                               const float* __restrict__ ew,
                               const float* __restrict__ dis,
                               int* __restrict__ cur,
                               int2* __restrict__ epk, int E) {
    int e = blockIdx.x * blockDim.x + threadIdx.x;
    if (e >= E) return;
    int r = row[e];
    int c = col[e];
    if (r == c) return;
    float nw = -dis[r] * ew[e] * dis[c];
    int pos = atomicAdd(&cur[c], 1);
    epk[pos] = make_int2(r, __float_as_int(nw));
}

// ---------------------------------------------------------------------------
// Atomic-free propagation: one wave per node, stream its CSR segment.
__global__ void gather_kernel(const int2* __restrict__ epk,
                              const int* __restrict__ rowstart,
                              const float2* __restrict__ h,
                              float2* __restrict__ o, int N) {
    int node = blockIdx.x * (blockDim.x >> 6) + (threadIdx.x >> 6);
    int lane = threadIdx.x & 63;
    if (node >= N) return;
    int s = rowstart[node];
    int t = rowstart[node + 1];
    float sx = 0.f, sy = 0.f;
    for (int i = s + lane; i < t; i += 64) {
        int2 p = epk[i];
        float w = __int_as_float(p.y);
        float2 hv = h[p.x];
        sx = fmaf(w, hv.x, sx);
        sy = fmaf(w, hv.y, sy);
    }
    for (int off = 32; off > 0; off >>= 1) {
        sx += __shfl_down(sx, off);
        sy += __shfl_down(sy, off);
    }
    if (lane == 0) o[node] = make_float2(sx, sy);
}

// Fallback propagation (atomic scatter), used only if ws is too small for CSR.
__global__ void prop_kernel(const int* __restrict__ row,
                            const int* __restrict__ col,
                            const float* __restrict__ ew,
                            const float* __restrict__ dis,
                            const float2* __restrict__ h,
                            float2* __restrict__ o, int E) {
    int e = blockIdx.x * blockDim.x + threadIdx.x;
    if (e >= E) return;
    int r = row[e];
    int c = col[e];
    if (r == c) return;
    float w = -dis[r] * ew[e] * dis[c];
    if (w == 0.f) return;
    float2 hv = h[r];
    atomicAdd(&o[c].x, w * hv.x);
    atomicAdd(&o[c].y, w * hv.y);
}

// ---------------------------------------------------------------------------
// Chebyshev node step: v = (tx0 ? 2*raw - tx0 : raw); raw = v; outacc += v@Wc[k].
__global__ void cheb_node_kernel(float2* __restrict__ raw,
                                 const float2* __restrict__ tx0,
                                 float2* __restrict__ outacc,
                                 const float* __restrict__ Wc,
                                 int k, int N) {
    int i = blockIdx.x * blockDim.x + threadIdx.x;
    if (i >= N) return;
    float2 v = raw[i];
    if (tx0) {
        float2 t = tx0[i];
        v.x = 2.f * v.x - t.x;
        v.y = 2.f * v.y - t.y;
        raw[i] = v;
    }
    float2 o = outacc[i];
    o.x += v.x * Wc[4 * k + 0] + v.y * Wc[4 * k + 2];
    o.y += v.x * Wc[4 * k + 1] + v.y * Wc[4 * k + 3];
    outacc[i] = o;
}

// ---------------------------------------------------------------------------
// u = x_turn*W0 + relu(out + cb)@W[1:3] + b; per-block max -> partials
__global__ void u_max_kernel(const float* __restrict__ x,
                             const float2* __restrict__ outacc,
                             const float* __restrict__ cb,
                             const float* __restrict__ W,
                             const float* __restrict__ b,
                             float* __restrict__ U,
                             float* __restrict__ partmax,
                             int N) {
    int i = blockIdx.x * blockDim.x + threadIdx.x;
    float u = -INFINITY;
    if (i < N) {
        float2 o = outacc[i];
        float h0 = fmaxf(o.x + cb[0], 0.f);
        float h1 = fmaxf(o.y + cb[1], 0.f);
        u = x[3 * i + 2] * W[0] + h0 * W[1] + h1 * W[2] + b[0];
        U[i] = u;
    }
    for (int off = 32; off > 0; off >>= 1) u = fmaxf(u, __shfl_down(u, off));
    __shared__ float s[THREADS / 64];
    if ((threadIdx.x & 63) == 0) s[threadIdx.x >> 6] = u;
    __syncthreads();
    if (threadIdx.x == 0) {
        float m = s[0];
        for (int w = 1; w < THREADS / 64; ++w) m = fmaxf(m, s[w]);
        partmax[blockIdx.x] = m;
    }
}

__global__ void reduce_max_kernel(const float* __restrict__ part, int n,
                                  float* __restrict__ dst) {
    float m = -INFINITY;
    for (int i = threadIdx.x; i < n; i += blockDim.x) m = fmaxf(m, part[i]);
    for (int off = 32; off > 0; off >>= 1) m = fmaxf(m, __shfl_down(m, off));
    __shared__ float s[16];
    int wid = threadIdx.x >> 6;
    if ((threadIdx.x & 63) == 0) s[wid] = m;
    __syncthreads();
    if (threadIdx.x == 0) {
        float r = s[0];
        int nw = blockDim.x >> 6;
        for (int w = 1; w < nw; ++w) r = fmaxf(r, s[w]);
        dst[0] = r;
    }
}

__global__ void exp_sum_kernel(float* __restrict__ U,
                               const float* __restrict__ gmax,
                               float* __restrict__ partsum, int N) {
    int i = blockIdx.x * blockDim.x + threadIdx.x;
    float e = 0.f;
    float m = gmax[0];
    if (i < N) {
        e = expf(U[i] - m);
        U[i] = e;
    }
    for (int off = 32; off > 0; off >>= 1) e += __shfl_down(e, off);
    __shared__ float s[THREADS / 64];
    if ((threadIdx.x & 63) == 0) s[threadIdx.x >> 6] = e;
    __syncthreads();
    if (threadIdx.x == 0) {
        float t = s[0];
        for (int w = 1; w < THREADS / 64; ++w) t += s[w];
        partsum[blockIdx.x] = t;
    }
}

__global__ void reduce_sum_kernel(const float* __restrict__ part, int n,
                                  float* __restrict__ dst) {
    float m = 0.f;
    for (int i = threadIdx.x; i < n; i += blockDim.x) m += part[i];
    for (int off = 32; off > 0; off >>= 1) m += __shfl_down(m, off);
    __shared__ float s[16];
    int wid = threadIdx.x >> 6;
    if ((threadIdx.x & 63) == 0) s[wid] = m;
    __syncthreads();
    if (threadIdx.x == 0) {
        float r = s[0];
        int nw = blockDim.x >> 6;
        for (int w = 1; w < nw; ++w) r += s[w];
        dst[0] = 1.f / r;
    }
}

__global__ void scale_kernel(const float* __restrict__ U,
                             const float* __restrict__ inv,
                             float* __restrict__ out, int N) {
    int i = blockIdx.x * blockDim.x + threadIdx.x;
    if (i < N) out[i] = U[i] * inv[0];
}

// ---------------------------------------------------------------------------
extern "C" void kernel_launch(void* const* d_in, const int* in_sizes, int n_in,
                              void* d_out, int out_size, void* d_ws, size_t ws_size,
                              hipStream_t stream) {
    (void)n_in; (void)out_size;
    const float* x    = (const float*)d_in[0];
    const int*   eidx = (const int*)d_in[1];     // int32 per harness contract
    const float* ew   = (const float*)d_in[2];
    const float* Wc   = (const float*)d_in[3];
    const float* cb   = (const float*)d_in[4];
    const float* W    = (const float*)d_in[5];
    const float* b    = (const float*)d_in[6];
    float*       out  = (float*)d_out;

    const int N = in_sizes[0] / 3;
    const int E = in_sizes[2];
    const int K = in_sizes[3] / 4;
    const int* row = eidx;
    const int* col = eidx + E;

    char* ws = (char*)d_ws;
    size_t off = 0;
    auto take = [&](size_t bytes) -> void* {
        void* p = ws + off;
        off = (off + bytes + 255) & ~(size_t)255;
        return p;
    };

    float*  deg      = (float*)take((size_t)N * 4);   // becomes dis after init
    float2* A        = (float2*)take((size_t)N * 8);
    float2* B        = (float2*)take((size_t)N * 8);
    float2* C        = (float2*)take((size_t)N * 8);
    float2* outacc   = (float2*)take((size_t)N * 8);
    float*  U        = (float*)take((size_t)N * 4);
    float*  part     = (float*)take(8192 * 4);
    float*  scal     = (float*)take(64 * 4);
    int*    cnt      = (int*)take((size_t)N * 4);
    int*    rowstart = (int*)take((size_t)(N + 1) * 4);
    int*    cur      = (int*)take((size_t)N * 4);
    int*    bsum     = (int*)take(512 * 4);
    int*    boff     = (int*)take(513 * 4);
    size_t  base_off = off;
    int2*   epk      = (int2*)take((size_t)E * 8);

    const int nb1 = (N + 255) / 256;             // scan1 block count
    const bool csr_ok = (off <= ws_size) && (nb1 <= 512);

    const int eb = (E + THREADS - 1) / THREADS;
    const int nb = (N + THREADS - 1) / THREADS;

    zero2_kernel<<<nb, THREADS, 0, stream>>>(deg, cnt, N);
    deg_cnt_kernel<<<eb, THREADS, 0, stream>>>(row, col, ew, deg, cnt, E);
    init_kernel<<<nb, THREADS, 0, stream>>>(x, deg, A, outacc, Wc, N);
    const float* dis = deg;

    if (csr_ok) {
        // ---- build CSR (col-sorted) ----
        scan1_kernel<<<nb1, 256, 0, stream>>>(cnt, rowstart, bsum, N);
        scan2_kernel<<<1, 512, 0, stream>>>(bsum, boff, nb1);
        scan3_kernel<<<(N + THREADS) / THREADS, THREADS, 0, stream>>>(rowstart, boff, cur, N, nb1);
        scatter_kernel<<<eb, THREADS, 0, stream>>>(row, col, ew, dis, cur, epk, E);

        const int gb = (N + 3) / 4;              // 4 waves per 256-thread block
        // k = 1
        gather_kernel<<<gb, THREADS, 0, stream>>>(epk, rowstart, A, B, N);
        cheb_node_kernel<<<nb, THREADS, 0, stream>>>(B, (const float2*)nullptr, outacc, Wc, 1, N);
        float2 *t0 = A, *t1 = B, *fr = C;
        for (int k = 2; k < K; ++k) {
            gather_kernel<<<gb, THREADS, 0, stream>>>(epk, rowstart, t1, fr, N);
            cheb_node_kernel<<<nb, THREADS, 0, stream>>>(fr, t0, outacc, Wc, k, N);
            float2* n0 = t1; float2* n1 = fr; float2* nf = t0;
            t0 = n0; t1 = n1; fr = nf;
        }
    } else {
        // ---- fallback: atomic scatter props (fits in base_off bytes) ----
        (void)base_off;
        // k = 1
        zerof2_kernel<<<nb, THREADS, 0, stream>>>(B, N);
        prop_kernel<<<eb, THREADS, 0, stream>>>(row, col, ew, dis, A, B, E);
        cheb_node_kernel<<<nb, THREADS, 0, stream>>>(B, (const float2*)nullptr, outacc, Wc, 1, N);
        float2 *t0 = A, *t1 = B, *fr = C;
        for (int k = 2; k < K; ++k) {
            zerof2_kernel<<<nb, THREADS, 0, stream>>>(fr, N);
            prop_kernel<<<eb, THREADS, 0, stream>>>(row, col, ew, dis, t1, fr, E);
            cheb_node_kernel<<<nb, THREADS, 0, stream>>>(fr, t0, outacc, Wc, k, N);
            float2* n0 = t1; float2* n1 = fr; float2* nf = t0;
            t0 = n0; t1 = n1; fr = nf;
        }
    }

    u_max_kernel<<<nb, THREADS, 0, stream>>>(x, outacc, cb, W, b, U, part, N);
    reduce_max_kernel<<<1, 1024, 0, stream>>>(part, nb, scal);
    exp_sum_kernel<<<nb, THREADS, 0, stream>>>(U, scal, part, N);
    reduce_sum_kernel<<<1, 1024, 0, stream>>>(part, nb, scal + 1);
    scale_kernel<<<nb, THREADS, 0, stream>>>(U, scal + 1, out, N);
}

// Round 6
// 589.457 us; speedup vs baseline: 4.9005x; 1.7798x over previous
//
#include <hip/hip_runtime.h>
#include <math.h>

#define THREADS 256
#define SB 512            // blocks for hist/scatter passes (chunked edge ranges)

// ---------------------------------------------------------------------------
// Per-block LDS histograms over node buckets (bucket = 256 nodes).
// TR[k*SB+b] = #edges in block b's chunk with row-bucket k (self-loops excl.)
// TC[k*SB+b] = same for col-bucket.
__global__ void hist_kernel(const int* __restrict__ row, const int* __restrict__ col,
                            int* __restrict__ TR, int* __restrict__ TC,
                            int E, int NB, int chunk) {
    extern __shared__ int sh[];
    int* hR = sh;
    int* hC = sh + NB;
    int t = threadIdx.x, b = blockIdx.x;
    for (int k = t; k < 2 * NB; k += THREADS) sh[k] = 0;
    __syncthreads();
    int lo = b * chunk;
    int hi = min(lo + chunk, E);
    for (int e = lo + t; e < hi; e += THREADS) {
        int r = row[e], c = col[e];
        if (r != c) {
            atomicAdd(&hR[r >> 8], 1);
            atomicAdd(&hC[c >> 8], 1);
        }
    }
    __syncthreads();
    for (int k = t; k < NB; k += THREADS) {
        TR[k * SB + b] = hR[k];
        TC[k * SB + b] = hC[k];
    }
}

// ---------------------------------------------------------------------------
// Exclusive scan over n elements, in place. 3 kernels; scan2 handles <=1024 chunks.
__global__ void scan1_kernel(int* __restrict__ data, int* __restrict__ bsum, int n) {
    __shared__ int s[256];
    int t = threadIdx.x;
    int i = blockIdx.x * 256 + t;
    int v = (i < n) ? data[i] : 0;
    s[t] = v;
    __syncthreads();
    for (int d = 1; d < 256; d <<= 1) {
        int xv = (t >= d) ? s[t - d] : 0;
        __syncthreads();
        s[t] += xv;
        __syncthreads();
    }
    if (i < n) data[i] = s[t] - v;               // block-local exclusive
    if (t == 255) bsum[blockIdx.x] = s[255];
}

__global__ void scan2_kernel(const int* __restrict__ bsum, int* __restrict__ boff, int nb) {
    __shared__ int s[1024];
    int t = threadIdx.x;
    int v = (t < nb) ? bsum[t] : 0;
    s[t] = v;
    __syncthreads();
    for (int d = 1; d < 1024; d <<= 1) {
        int xv = (t >= d) ? s[t - d] : 0;
        __syncthreads();
        s[t] += xv;
        __syncthreads();
    }
    if (t < nb) boff[t] = s[t] - v;
    if (t == nb - 1) boff[nb] = s[t];            // grand total
}

__global__ void scan3_kernel(int* __restrict__ data, const int* __restrict__ boff,
                             int n, int nbk) {
    int i = blockIdx.x * blockDim.x + threadIdx.x;
    if (i < n) data[i] += boff[i >> 8];
    else if (i == n) data[n] = boff[nbk];        // append grand total
}

// ---------------------------------------------------------------------------
// Scatter edges into bucket-grouped record streams. Cursors live in LDS
// (per-block ranges are disjoint by construction -> no global atomics).
__global__ void scatter_both_kernel(const int* __restrict__ row, const int* __restrict__ col,
                                    const float* __restrict__ ew,
                                    const int* __restrict__ TR, const int* __restrict__ TC,
                                    int2* __restrict__ rrec, int2* __restrict__ crec,
                                    int E, int NB, int chunk) {
    extern __shared__ int sh[];
    int* cR = sh;
    int* cC = sh + NB;
    int t = threadIdx.x, b = blockIdx.x;
    for (int k = t; k < NB; k += THREADS) {
        cR[k] = TR[k * SB + b];
        cC[k] = TC[k * SB + b];
    }
    __syncthreads();
    int lo = b * chunk;
    int hi = min(lo + chunk, E);
    for (int e = lo + t; e < hi; e += THREADS) {
        int r = row[e], c = col[e];
        if (r == c) continue;
        float w = ew[e];
        int pr = atomicAdd(&cR[r >> 8], 1);
        rrec[pr] = make_int2(r & 255, __float_as_int(w));
        int pc = atomicAdd(&cC[c >> 8], 1);
        crec[pc] = make_int2((r << 8) | (c & 255), __float_as_int(w));
    }
}

// mode 0: row records {row_local, ew}; mode 1: col records {row<<8|col_local, ew}
__global__ void scatter_one_kernel(const int* __restrict__ row, const int* __restrict__ col,
                                   const float* __restrict__ ew,
                                   const int* __restrict__ T, int2* __restrict__ rec,
                                   int E, int NB, int chunk, int mode) {
    extern __shared__ int sh[];
    int t = threadIdx.x, b = blockIdx.x;
    for (int k = t; k < NB; k += THREADS) sh[k] = T[k * SB + b];
    __syncthreads();
    int lo = b * chunk;
    int hi = min(lo + chunk, E);
    for (int e = lo + t; e < hi; e += THREADS) {
        int r = row[e], c = col[e];
        if (r == c) continue;
        float w = ew[e];
        if (mode == 0) {
            int p = atomicAdd(&sh[r >> 8], 1);
            rec[p] = make_int2(r & 255, __float_as_int(w));
        } else {
            int p = atomicAdd(&sh[c >> 8], 1);
            rec[p] = make_int2((r << 8) | (c & 255), __float_as_int(w));
        }
    }
}

// ---------------------------------------------------------------------------
// deg: one block per row-bucket, LDS accumulate, plain store.
__global__ void degreduce_kernel(const int2* __restrict__ rec, const int* __restrict__ TR,
                                 float* __restrict__ deg, int N) {
    __shared__ float sacc[256];
    int t = threadIdx.x, bk = blockIdx.x;
    sacc[t] = 0.f;
    __syncthreads();
    int s = TR[bk * SB];
    int e = TR[(bk + 1) * SB];
    for (int i = s + t; i < e; i += 256) {
        int2 p = rec[i];
        atomicAdd(&sacc[p.x], __int_as_float(p.y));
    }
    __syncthreads();
    int node = bk * 256 + t;
    if (node < N) deg[node] = sacc[t];
}

// ---------------------------------------------------------------------------
// Per-node init: deg -> dis (in place), Tx0 = x[:, :2], outacc = Tx0 @ Wc[0].
__global__ void init_kernel(const float* __restrict__ x,
                            float* __restrict__ deg,        // becomes dis
                            float2* __restrict__ tx0,
                            float2* __restrict__ outacc,
                            const float* __restrict__ Wc,
                            int N) {
    int i = blockIdx.x * blockDim.x + threadIdx.x;
    if (i >= N) return;
    float d = deg[i];
    deg[i] = (d > 0.f) ? rsqrtf(d) : 0.f;
    float x0 = x[3 * i + 0];
    float x1 = x[3 * i + 1];
    tx0[i] = make_float2(x0, x1);
    outacc[i] = make_float2(x0 * Wc[0] + x1 * Wc[2],
                            x0 * Wc[1] + x1 * Wc[3]);
}

// ---------------------------------------------------------------------------
// Propagation: one block per col-bucket; coalesced record stream, L2-resident
// dis/h gathers, LDS accumulation, plain stores. Zero global atomics.
__global__ void gather_kernel(const int2* __restrict__ rec, const int* __restrict__ TC,
                              const float* __restrict__ dis, const float2* __restrict__ h,
                              float2* __restrict__ o, int N) {
    __shared__ float sdis[256], sax[256], say[256];
    int t = threadIdx.x, bk = blockIdx.x;
    int node = bk * 256 + t;
    sdis[t] = (node < N) ? dis[node] : 0.f;
    sax[t] = 0.f;
    say[t] = 0.f;
    __syncthreads();
    int s = TC[bk * SB];
    int e = TC[(bk + 1) * SB];
    for (int i = s + t; i < e; i += 256) {
        int2 p = rec[i];
        int r  = p.x >> 8;
        int cl = p.x & 255;
        float w = -dis[r] * __int_as_float(p.y) * sdis[cl];
        float2 hv = h[r];
        atomicAdd(&sax[cl], w * hv.x);
        atomicAdd(&say[cl], w * hv.y);
    }
    __syncthreads();
    if (node < N) o[node] = make_float2(sax[t], say[t]);
}

// ---------------------------------------------------------------------------
// Full-atomic fallback kernels (only if workspace is too small).
__global__ void zero_kernel(float* __restrict__ p, int n) {
    int i = blockIdx.x * blockDim.x + threadIdx.x;
    if (i < n) p[i] = 0.f;
}
__global__ void zerof2_kernel(float2* __restrict__ p, int n) {
    int i = blockIdx.x * blockDim.x + threadIdx.x;
    if (i < n) p[i] = make_float2(0.f, 0.f);
}
__global__ void deg_at_kernel(const int* __restrict__ row, const int* __restrict__ col,
                              const float* __restrict__ ew, float* __restrict__ deg, int E) {
    int e = blockIdx.x * blockDim.x + threadIdx.x;
    if (e >= E) return;
    int r = row[e], c = col[e];
    if (r != c) atomicAdd(&deg[r], ew[e]);
}
__global__ void prop_kernel(const int* __restrict__ row, const int* __restrict__ col,
                            const float* __restrict__ ew, const float* __restrict__ dis,
                            const float2* __restrict__ h, float2* __restrict__ o, int E) {
    int e = blockIdx.x * blockDim.x + threadIdx.x;
    if (e >= E) return;
    int r = row[e], c = col[e];
    if (r == c) return;
    float w = -dis[r] * ew[e] * dis[c];
    if (w == 0.f) return;
    float2 hv = h[r];
    atomicAdd(&o[c].x, w * hv.x);
    atomicAdd(&o[c].y, w * hv.y);
}

// ---------------------------------------------------------------------------
// Chebyshev node step: v = (tx0 ? 2*raw - tx0 : raw); raw = v; outacc += v@Wc[k].
__global__ void cheb_node_kernel(float2* __restrict__ raw,
                                 const float2* __restrict__ tx0,
                                 float2* __restrict__ outacc,
                                 const float* __restrict__ Wc,
                                 int k, int N) {
    int i = blockIdx.x * blockDim.x + threadIdx.x;
    if (i >= N) return;
    float2 v = raw[i];
    if (tx0) {
        float2 t = tx0[i];
        v.x = 2.f * v.x - t.x;
        v.y = 2.f * v.y - t.y;
        raw[i] = v;
    }
    float2 o = outacc[i];
    o.x += v.x * Wc[4 * k + 0] + v.y * Wc[4 * k + 2];
    o.y += v.x * Wc[4 * k + 1] + v.y * Wc[4 * k + 3];
    outacc[i] = o;
}

// ---------------------------------------------------------------------------
// Epilogue: u = x_turn*W0 + relu(out + cb)@W[1:3] + b; softmax over N.
__global__ void u_max_kernel(const float* __restrict__ x,
                             const float2* __restrict__ outacc,
                             const float* __restrict__ cb,
                             const float* __restrict__ W,
                             const float* __restrict__ b,
                             float* __restrict__ U,
                             float* __restrict__ partmax,
                             int N) {
    int i = blockIdx.x * blockDim.x + threadIdx.x;
    float u = -INFINITY;
    if (i < N) {
        float2 o = outacc[i];
        float h0 = fmaxf(o.x + cb[0], 0.f);
        float h1 = fmaxf(o.y + cb[1], 0.f);
        u = x[3 * i + 2] * W[0] + h0 * W[1] + h1 * W[2] + b[0];
        U[i] = u;
    }
    for (int off = 32; off > 0; off >>= 1) u = fmaxf(u, __shfl_down(u, off));
    __shared__ float s[THREADS / 64];
    if ((threadIdx.x & 63) == 0) s[threadIdx.x >> 6] = u;
    __syncthreads();
    if (threadIdx.x == 0) {
        float m = s[0];
        for (int w = 1; w < THREADS / 64; ++w) m = fmaxf(m, s[w]);
        partmax[blockIdx.x] = m;
    }
}

__global__ void reduce_max_kernel(const float* __restrict__ part, int n,
                                  float* __restrict__ dst) {
    float m = -INFINITY;
    for (int i = threadIdx.x; i < n; i += blockDim.x) m = fmaxf(m, part[i]);
    for (int off = 32; off > 0; off >>= 1) m = fmaxf(m, __shfl_down(m, off));
    __shared__ float s[16];
    int wid = threadIdx.x >> 6;
    if ((threadIdx.x & 63) == 0) s[wid] = m;
    __syncthreads();
    if (threadIdx.x == 0) {
        float r = s[0];
        int nw = blockDim.x >> 6;
        for (int w = 1; w < nw; ++w) r = fmaxf(r, s[w]);
        dst[0] = r;
    }
}

__global__ void exp_sum_kernel(float* __restrict__ U,
                               const float* __restrict__ gmax,
                               float* __restrict__ partsum, int N) {
    int i = blockIdx.x * blockDim.x + threadIdx.x;
    float e = 0.f;
    float m = gmax[0];
    if (i < N) {
        e = expf(U[i] - m);
        U[i] = e;
    }
    for (int off = 32; off > 0; off >>= 1) e += __shfl_down(e, off);
    __shared__ float s[THREADS / 64];
    if ((threadIdx.x & 63) == 0) s[threadIdx.x >> 6] = e;
    __syncthreads();
    if (threadIdx.x == 0) {
        float t = s[0];
        for (int w = 1; w < THREADS / 64; ++w) t += s[w];
        partsum[blockIdx.x] = t;
    }
}

__global__ void reduce_sum_kernel(const float* __restrict__ part, int n,
                                  float* __restrict__ dst) {
    float m = 0.f;
    for (int i = threadIdx.x; i < n; i += blockDim.x) m += part[i];
    for (int off = 32; off > 0; off >>= 1) m += __shfl_down(m, off);
    __shared__ float s[16];
    int wid = threadIdx.x >> 6;
    if ((threadIdx.x & 63) == 0) s[wid] = m;
    __syncthreads();
    if (threadIdx.x == 0) {
        float r = s[0];
        int nw = blockDim.x >> 6;
        for (int w = 1; w < nw; ++w) r += s[w];
        dst[0] = 1.f / r;
    }
}

__global__ void scale_kernel(const float* __restrict__ U,
                             const float* __restrict__ inv,
                             float* __restrict__ out, int N) {
    int i = blockIdx.x * blockDim.x + threadIdx.x;
    if (i < N) out[i] = U[i] * inv[0];
}

// ---------------------------------------------------------------------------
extern "C" void kernel_launch(void* const* d_in, const int* in_sizes, int n_in,
                              void* d_out, int out_size, void* d_ws, size_t ws_size,
                              hipStream_t stream) {
    (void)n_in; (void)out_size;
    const float* x    = (const float*)d_in[0];
    const int*   eidx = (const int*)d_in[1];     // int32 per harness contract
    const float* ew   = (const float*)d_in[2];
    const float* Wc   = (const float*)d_in[3];
    const float* cb   = (const float*)d_in[4];
    const float* W    = (const float*)d_in[5];
    const float* b    = (const float*)d_in[6];
    float*       out  = (float*)d_out;

    const int N = in_sizes[0] / 3;
    const int E = in_sizes[2];
    const int K = in_sizes[3] / 4;
    const int* row = eidx;
    const int* col = eidx + E;

    const int NB    = (N + 255) >> 8;            // node buckets of 256
    const int n     = NB * SB;                   // count-table length
    const int nblk1 = (n + 255) / 256;           // scan chunks
    const int chunk = (E + SB - 1) / SB;

    char* ws = (char*)d_ws;
    size_t off = 0;
    auto take = [&](size_t bytes) -> void* {
        void* p = ws + off;
        off = (off + bytes + 255) & ~(size_t)255;
        return p;
    };

    float*  deg    = (float*)take((size_t)N * 4);   // becomes dis after init
    float2* A      = (float2*)take((size_t)N * 8);
    float2* B      = (float2*)take((size_t)N * 8);
    float2* C      = (float2*)take((size_t)N * 8);
    float2* outacc = (float2*)take((size_t)N * 8);
    float*  U      = (float*)take((size_t)N * 4);
    float*  part   = (float*)take(8192 * 4);
    float*  scal   = (float*)take(64 * 4);
    int*    TR     = (int*)take((size_t)(n + 1) * 4);
    int*    TC     = (int*)take((size_t)(n + 1) * 4);
    int*    bsum   = (int*)take(1024 * 4);
    int*    boff   = (int*)take(1025 * 4);
    int2*   crec   = (int2*)take((size_t)E * 8);
    size_t  off1   = off;
    int2*   rrec   = (int2*)take((size_t)E * 8);
    size_t  off2   = off;

    const bool bucket_ok = (nblk1 <= 1024) && (N < (1 << 17)) && (NB >= 1);
    const bool merged    = bucket_ok && (off2 <= ws_size);
    const bool seq       = bucket_ok && !merged && (off1 <= ws_size);

    const int eb = (E + THREADS - 1) / THREADS;
    const int nb = (N + THREADS - 1) / THREADS;
    const int sg = (n + 256) / 256;              // scan3 grid (covers i == n)

    if (merged || seq) {
        hist_kernel<<<SB, THREADS, 2 * NB * 4, stream>>>(row, col, TR, TC, E, NB, chunk);
        scan1_kernel<<<nblk1, 256, 0, stream>>>(TR, bsum, n);
        scan2_kernel<<<1, 1024, 0, stream>>>(bsum, boff, nblk1);
        scan3_kernel<<<sg, 256, 0, stream>>>(TR, boff, n, nblk1);
        scan1_kernel<<<nblk1, 256, 0, stream>>>(TC, bsum, n);
        scan2_kernel<<<1, 1024, 0, stream>>>(bsum, boff, nblk1);
        scan3_kernel<<<sg, 256, 0, stream>>>(TC, boff, n, nblk1);

        if (merged) {
            scatter_both_kernel<<<SB, THREADS, 2 * NB * 4, stream>>>(
                row, col, ew, TR, TC, rrec, crec, E, NB, chunk);
            degreduce_kernel<<<NB, 256, 0, stream>>>(rrec, TR, deg, N);
            init_kernel<<<nb, THREADS, 0, stream>>>(x, deg, A, outacc, Wc, N);
        } else {
            scatter_one_kernel<<<SB, THREADS, NB * 4, stream>>>(
                row, col, ew, TR, crec, E, NB, chunk, 0);
            degreduce_kernel<<<NB, 256, 0, stream>>>(crec, TR, deg, N);
            init_kernel<<<nb, THREADS, 0, stream>>>(x, deg, A, outacc, Wc, N);
            scatter_one_kernel<<<SB, THREADS, NB * 4, stream>>>(
                row, col, ew, TC, crec, E, NB, chunk, 1);
        }
        const float* dis = deg;

        // k = 1
        gather_kernel<<<NB, 256, 0, stream>>>(crec, TC, dis, A, B, N);
        cheb_node_kernel<<<nb, THREADS, 0, stream>>>(B, (const float2*)nullptr, outacc, Wc, 1, N);
        float2 *t0 = A, *t1 = B, *fr = C;
        for (int k = 2; k < K; ++k) {
            gather_kernel<<<NB, 256, 0, stream>>>(crec, TC, dis, t1, fr, N);
            cheb_node_kernel<<<nb, THREADS, 0, stream>>>(fr, t0, outacc, Wc, k, N);
            float2* n0 = t1; float2* n1 = fr; float2* nf = t0;
            t0 = n0; t1 = n1; fr = nf;
        }
    } else {
        // ---- full-atomic fallback ----
        zero_kernel<<<nb, THREADS, 0, stream>>>(deg, N);
        deg_at_kernel<<<eb, THREADS, 0, stream>>>(row, col, ew, deg, E);
        init_kernel<<<nb, THREADS, 0, stream>>>(x, deg, A, outacc, Wc, N);
        const float* dis = deg;
        zerof2_kernel<<<nb, THREADS, 0, stream>>>(B, N);
        prop_kernel<<<eb, THREADS, 0, stream>>>(row, col, ew, dis, A, B, E);
        cheb_node_kernel<<<nb, THREADS, 0, stream>>>(B, (const float2*)nullptr, outacc, Wc, 1, N);
        float2 *t0 = A, *t1 = B, *fr = C;
        for (int k = 2; k < K; ++k) {
            zerof2_kernel<<<nb, THREADS, 0, stream>>>(fr, N);
            prop_kernel<<<eb, THREADS, 0, stream>>>(row, col, ew, dis, t1, fr, E);
            cheb_node_kernel<<<nb, THREADS, 0, stream>>>(fr, t0, outacc, Wc, k, N);
            float2* n0 = t1; float2* n1 = fr; float2* nf = t0;
            t0 = n0; t1 = n1; fr = nf;
        }
    }

    u_max_kernel<<<nb, THREADS, 0, stream>>>(x, outacc, cb, W, b, U, part, N);
    reduce_max_kernel<<<1, 1024, 0, stream>>>(part, nb, scal);
    exp_sum_kernel<<<nb, THREADS, 0, stream>>>(U, scal, part, N);
    reduce_sum_kernel<<<1, 1024, 0, stream>>>(part, nb, scal + 1);
    scale_kernel<<<nb, THREADS, 0, stream>>>(U, scal + 1, out, N);
}

// Round 7
// 513.332 us; speedup vs baseline: 5.6273x; 1.1483x over previous
//
#include <hip/hip_runtime.h>
#include <math.h>

#define THREADS 256
#define SB 1024           // blocks for hist/scatter passes (chunked edge ranges)
#define BSH 10            // bucket shift: 1024 nodes per bucket
#define BSZ 1024
#define BMSK 1023

// ---------------------------------------------------------------------------
// Per-block LDS histograms over node buckets (bucket = 1024 nodes).
// TU[k*SB+b]       = #edges in block b's chunk with row-bucket k (self excl.)
// TU[(NB+k)*SB+b]  = same for col-bucket.
__global__ void hist_kernel(const int* __restrict__ row, const int* __restrict__ col,
                            int* __restrict__ TU, int E, int NB, int chunk) {
    extern __shared__ int sh[];
    int t = threadIdx.x, b = blockIdx.x;
    for (int k = t; k < 2 * NB; k += THREADS) sh[k] = 0;
    __syncthreads();
    int lo = b * chunk;
    int hi = min(lo + chunk, E);
    for (int e = lo + t; e < hi; e += THREADS) {
        int r = row[e], c = col[e];
        if (r != c) {
            atomicAdd(&sh[r >> BSH], 1);
            atomicAdd(&sh[NB + (c >> BSH)], 1);
        }
    }
    __syncthreads();
    for (int k = t; k < 2 * NB; k += THREADS) TU[k * SB + b] = sh[k];
}

// ---------------------------------------------------------------------------
// Exclusive scan over n elements, in place. scan2 handles <=1024 chunks.
__global__ void scan1_kernel(int* __restrict__ data, int* __restrict__ bsum, int n) {
    __shared__ int s[256];
    int t = threadIdx.x;
    int i = blockIdx.x * 256 + t;
    int v = (i < n) ? data[i] : 0;
    s[t] = v;
    __syncthreads();
    for (int d = 1; d < 256; d <<= 1) {
        int xv = (t >= d) ? s[t - d] : 0;
        __syncthreads();
        s[t] += xv;
        __syncthreads();
    }
    if (i < n) data[i] = s[t] - v;               // block-local exclusive
    if (t == 255) bsum[blockIdx.x] = s[255];
}

__global__ void scan2_kernel(const int* __restrict__ bsum, int* __restrict__ boff, int nb) {
    __shared__ int s[1024];
    int t = threadIdx.x;
    int v = (t < nb) ? bsum[t] : 0;
    s[t] = v;
    __syncthreads();
    for (int d = 1; d < 1024; d <<= 1) {
        int xv = (t >= d) ? s[t - d] : 0;
        __syncthreads();
        s[t] += xv;
        __syncthreads();
    }
    if (t < nb) boff[t] = s[t] - v;
    if (t == nb - 1) boff[nb] = s[t];            // grand total
}

__global__ void scan3_kernel(int* __restrict__ data, const int* __restrict__ boff,
                             int n, int nbk) {
    int i = blockIdx.x * blockDim.x + threadIdx.x;
    if (i < n) data[i] += boff[i >> 8];
    else if (i == n) data[n] = boff[nbk];        // append grand total
}

// ---------------------------------------------------------------------------
// Scatter edges into bucket-grouped unified record stream (row recs then col
// recs). Cursors in LDS; per-block ranges disjoint -> no global atomics.
__global__ void scatter_kernel(const int* __restrict__ row, const int* __restrict__ col,
                               const float* __restrict__ ew,
                               const int* __restrict__ TU, int2* __restrict__ rec,
                               int E, int NB, int chunk) {
    extern __shared__ int sh[];
    int t = threadIdx.x, b = blockIdx.x;
    for (int k = t; k < 2 * NB; k += THREADS) sh[k] = TU[k * SB + b];
    __syncthreads();
    int lo = b * chunk;
    int hi = min(lo + chunk, E);
    for (int e = lo + t; e < hi; e += THREADS) {
        int r = row[e], c = col[e];
        if (r == c) continue;
        float w = ew[e];
        int pr = atomicAdd(&sh[r >> BSH], 1);
        rec[pr] = make_int2(r & BMSK, __float_as_int(w));
        int pc = atomicAdd(&sh[NB + (c >> BSH)], 1);
        rec[pc] = make_int2((r << BSH) | (c & BMSK), __float_as_int(w));
    }
}

// ---------------------------------------------------------------------------
// deg partials: grid = NB*M sub-blocks; LDS accumulate a record slice, plain
// writes to pdeg[(bk*M+m)*BSZ + local].
__global__ void degred_kernel(const int2* __restrict__ rec, const int* __restrict__ TU,
                              float* __restrict__ pdeg, int M) {
    __shared__ float acc[BSZ];
    int t = threadIdx.x;
    int bk = blockIdx.x / M, m = blockIdx.x % M;
    for (int j = t; j < BSZ; j += THREADS) acc[j] = 0.f;
    __syncthreads();
    int s = TU[bk * SB];
    int e2 = TU[(bk + 1) * SB];
    int len = e2 - s;
    int lo = s + (int)((long long)len * m / M);
    int hi = s + (int)((long long)len * (m + 1) / M);
    for (int i = lo + t; i < hi; i += THREADS) {
        int2 p = rec[i];
        atomicAdd(&acc[p.x], __int_as_float(p.y));
    }
    __syncthreads();
    float* dst = pdeg + (size_t)(bk * M + m) * BSZ;
    for (int j = t; j < BSZ; j += THREADS) dst[j] = acc[j];
}

// ---------------------------------------------------------------------------
// init (fused deg-partial reduce): dis = rsqrt(sum pdeg); Tx0 = x[:, :2];
// outacc = Tx0 @ Wc[0].
__global__ void init_kernel(const float* __restrict__ x, const float* __restrict__ pdeg,
                            float* __restrict__ dis, float2* __restrict__ tx0,
                            float2* __restrict__ outacc, const float* __restrict__ Wc,
                            int N, int M) {
    int i = blockIdx.x * blockDim.x + threadIdx.x;
    if (i >= N) return;
    int bk = i >> BSH, li = i & BMSK;
    const float* src = pdeg + (size_t)bk * M * BSZ + li;
    float d = 0.f;
    for (int m = 0; m < M; ++m) d += src[(size_t)m * BSZ];
    dis[i] = (d > 0.f) ? rsqrtf(d) : 0.f;
    float x0 = x[3 * i + 0];
    float x1 = x[3 * i + 1];
    tx0[i] = make_float2(x0, x1);
    outacc[i] = make_float2(x0 * Wc[0] + x1 * Wc[2],
                            x0 * Wc[1] + x1 * Wc[3]);
}

// ---------------------------------------------------------------------------
// Propagation partials: grid = NB*M; LDS accumulate norm*h over a col-record
// slice; plain float2 writes. Zero global atomics.
__global__ void gather_kernel(const int2* __restrict__ rec, const int* __restrict__ TU,
                              const float* __restrict__ dis, const float2* __restrict__ h,
                              float2* __restrict__ pprop, int N, int NB, int M) {
    __shared__ float2 acc[BSZ];
    __shared__ float sdis[BSZ];
    int t = threadIdx.x;
    int bk = blockIdx.x / M, m = blockIdx.x % M;
    for (int j = t; j < BSZ; j += THREADS) {
        acc[j] = make_float2(0.f, 0.f);
        int node = (bk << BSH) + j;
        sdis[j] = (node < N) ? dis[node] : 0.f;
    }
    __syncthreads();
    int s = TU[(NB + bk) * SB];
    int e2 = TU[(NB + bk + 1) * SB];
    int len = e2 - s;
    int lo = s + (int)((long long)len * m / M);
    int hi = s + (int)((long long)len * (m + 1) / M);
    for (int i = lo + t; i < hi; i += THREADS) {
        int2 p = rec[i];
        int r  = ((unsigned)p.x) >> BSH;
        int cl = p.x & BMSK;
        float w = -dis[r] * __int_as_float(p.y) * sdis[cl];
        float2 hv = h[r];
        atomicAdd(&acc[cl].x, w * hv.x);
        atomicAdd(&acc[cl].y, w * hv.y);
    }
    __syncthreads();
    float2* dst = pprop + (size_t)(bk * M + m) * BSZ;
    for (int j = t; j < BSZ; j += THREADS) dst[j] = acc[j];
}

// ---------------------------------------------------------------------------
// Chebyshev node step (fused partial reduce): v = sum_m pprop;
// v = 2v - tx0 (if k>=2); txk = v; outacc += v @ Wc[k].
__global__ void cheb_kernel(const float2* __restrict__ pprop, const float2* __restrict__ tx0,
                            float2* __restrict__ txk, float2* __restrict__ outacc,
                            const float* __restrict__ Wc, int k, int N, int M) {
    int i = blockIdx.x * blockDim.x + threadIdx.x;
    if (i >= N) return;
    int bk = i >> BSH, li = i & BMSK;
    const float2* src = pprop + (size_t)bk * M * BSZ + li;
    float2 v = make_float2(0.f, 0.f);
    for (int m = 0; m < M; ++m) {
        float2 p = src[(size_t)m * BSZ];
        v.x += p.x;
        v.y += p.y;
    }
    if (tx0) {
        float2 tv = tx0[i];
        v.x = 2.f * v.x - tv.x;
        v.y = 2.f * v.y - tv.y;
    }
    txk[i] = v;
    float2 o = outacc[i];
    o.x += v.x * Wc[4 * k + 0] + v.y * Wc[4 * k + 2];
    o.y += v.x * Wc[4 * k + 1] + v.y * Wc[4 * k + 3];
    outacc[i] = o;
}

// ---------------------------------------------------------------------------
// Full-atomic fallback kernels (only if workspace is too small).
__global__ void zero_kernel(float* __restrict__ p, int n) {
    int i = blockIdx.x * blockDim.x + threadIdx.x;
    if (i < n) p[i] = 0.f;
}
__global__ void zerof2_kernel(float2* __restrict__ p, int n) {
    int i = blockIdx.x * blockDim.x + threadIdx.x;
    if (i < n) p[i] = make_float2(0.f, 0.f);
}
__global__ void deg_at_kernel(const int* __restrict__ row, const int* __restrict__ col,
                              const float* __restrict__ ew, float* __restrict__ deg, int E) {
    int e = blockIdx.x * blockDim.x + threadIdx.x;
    if (e >= E) return;
    int r = row[e], c = col[e];
    if (r != c) atomicAdd(&deg[r], ew[e]);
}
__global__ void init_at_kernel(const float* __restrict__ x, float* __restrict__ deg,
                               float2* __restrict__ tx0, float2* __restrict__ outacc,
                               const float* __restrict__ Wc, int N) {
    int i = blockIdx.x * blockDim.x + threadIdx.x;
    if (i >= N) return;
    float d = deg[i];
    deg[i] = (d > 0.f) ? rsqrtf(d) : 0.f;
    float x0 = x[3 * i + 0];
    float x1 = x[3 * i + 1];
    tx0[i] = make_float2(x0, x1);
    outacc[i] = make_float2(x0 * Wc[0] + x1 * Wc[2],
                            x0 * Wc[1] + x1 * Wc[3]);
}
__global__ void prop_kernel(const int* __restrict__ row, const int* __restrict__ col,
                            const float* __restrict__ ew, const float* __restrict__ dis,
                            const float2* __restrict__ h, float2* __restrict__ o, int E) {
    int e = blockIdx.x * blockDim.x + threadIdx.x;
    if (e >= E) return;
    int r = row[e], c = col[e];
    if (r == c) return;
    float w = -dis[r] * ew[e] * dis[c];
    if (w == 0.f) return;
    float2 hv = h[r];
    atomicAdd(&o[c].x, w * hv.x);
    atomicAdd(&o[c].y, w * hv.y);
}
__global__ void cheb_at_kernel(float2* __restrict__ raw, const float2* __restrict__ tx0,
                               float2* __restrict__ outacc, const float* __restrict__ Wc,
                               int k, int N) {
    int i = blockIdx.x * blockDim.x + threadIdx.x;
    if (i >= N) return;
    float2 v = raw[i];
    if (tx0) {
        float2 t = tx0[i];
        v.x = 2.f * v.x - t.x;
        v.y = 2.f * v.y - t.y;
        raw[i] = v;
    }
    float2 o = outacc[i];
    o.x += v.x * Wc[4 * k + 0] + v.y * Wc[4 * k + 2];
    o.y += v.x * Wc[4 * k + 1] + v.y * Wc[4 * k + 3];
    outacc[i] = o;
}

// ---------------------------------------------------------------------------
// Epilogue: u = x_turn*W0 + relu(out + cb)@W[1:3] + b; softmax over N.
__global__ void u_max_kernel(const float* __restrict__ x, const float2* __restrict__ outacc,
                             const float* __restrict__ cb, const float* __restrict__ W,
                             const float* __restrict__ b, float* __restrict__ U,
                             float* __restrict__ partmax, int N) {
    int i = blockIdx.x * blockDim.x + threadIdx.x;
    float u = -INFINITY;
    if (i < N) {
        float2 o = outacc[i];
        float h0 = fmaxf(o.x + cb[0], 0.f);
        float h1 = fmaxf(o.y + cb[1], 0.f);
        u = x[3 * i + 2] * W[0] + h0 * W[1] + h1 * W[2] + b[0];
        U[i] = u;
    }
    for (int off = 32; off > 0; off >>= 1) u = fmaxf(u, __shfl_down(u, off));
    __shared__ float s[THREADS / 64];
    if ((threadIdx.x & 63) == 0) s[threadIdx.x >> 6] = u;
    __syncthreads();
    if (threadIdx.x == 0) {
        float m = s[0];
        for (int w = 1; w < THREADS / 64; ++w) m = fmaxf(m, s[w]);
        partmax[blockIdx.x] = m;
    }
}

__global__ void reduce_max_kernel(const float* __restrict__ part, int n,
                                  float* __restrict__ dst) {
    float m = -INFINITY;
    for (int i = threadIdx.x; i < n; i += blockDim.x) m = fmaxf(m, part[i]);
    for (int off = 32; off > 0; off >>= 1) m = fmaxf(m, __shfl_down(m, off));
    __shared__ float s[16];
    int wid = threadIdx.x >> 6;
    if ((threadIdx.x & 63) == 0) s[wid] = m;
    __syncthreads();
    if (threadIdx.x == 0) {
        float r = s[0];
        int nw = blockDim.x >> 6;
        for (int w = 1; w < nw; ++w) r = fmaxf(r, s[w]);
        dst[0] = r;
    }
}

__global__ void exp_sum_kernel(float* __restrict__ U, const float* __restrict__ gmax,
                               float* __restrict__ partsum, int N) {
    int i = blockIdx.x * blockDim.x + threadIdx.x;
    float e = 0.f;
    float m = gmax[0];
    if (i < N) {
        e = expf(U[i] - m);
        U[i] = e;
    }
    for (int off = 32; off > 0; off >>= 1) e += __shfl_down(e, off);
    __shared__ float s[THREADS / 64];
    if ((threadIdx.x & 63) == 0) s[threadIdx.x >> 6] = e;
    __syncthreads();
    if (threadIdx.x == 0) {
        float t = s[0];
        for (int w = 1; w < THREADS / 64; ++w) t += s[w];
        partsum[blockIdx.x] = t;
    }
}

__global__ void reduce_sum_kernel(const float* __restrict__ part, int n,
                                  float* __restrict__ dst) {
    float m = 0.f;
    for (int i = threadIdx.x; i < n; i += blockDim.x) m += part[i];
    for (int off = 32; off > 0; off >>= 1) m += __shfl_down(m, off);
    __shared__ float s[16];
    int wid = threadIdx.x >> 6;
    if ((threadIdx.x & 63) == 0) s[wid] = m;
    __syncthreads();
    if (threadIdx.x == 0) {
        float r = s[0];
        int nw = blockDim.x >> 6;
        for (int w = 1; w < nw; ++w) r += s[w];
        dst[0] = 1.f / r;
    }
}

__global__ void scale_kernel(const float* __restrict__ U, const float* __restrict__ inv,
                             float* __restrict__ out, int N) {
    int i = blockIdx.x * blockDim.x + threadIdx.x;
    if (i < N) out[i] = U[i] * inv[0];
}

// ---------------------------------------------------------------------------
extern "C" void kernel_launch(void* const* d_in, const int* in_sizes, int n_in,
                              void* d_out, int out_size, void* d_ws, size_t ws_size,
                              hipStream_t stream) {
    (void)n_in; (void)out_size;
    const float* x    = (const float*)d_in[0];
    const int*   eidx = (const int*)d_in[1];     // int32 per harness contract
    const float* ew   = (const float*)d_in[2];
    const float* Wc   = (const float*)d_in[3];
    const float* cb   = (const float*)d_in[4];
    const float* W    = (const float*)d_in[5];
    const float* b    = (const float*)d_in[6];
    float*       out  = (float*)d_out;

    const int N = in_sizes[0] / 3;
    const int E = in_sizes[2];
    const int K = in_sizes[3] / 4;
    const int* row = eidx;
    const int* col = eidx + E;

    const int NB    = (N + BMSK) >> BSH;         // 1024-node buckets
    const int n2    = 2 * NB * SB;               // unified count-table length
    const int nblk  = (n2 + 255) / 256;
    const int chunk = (E + SB - 1) / SB;
    const int Npad  = NB << BSH;

    char* ws = (char*)d_ws;
    size_t off = 0;
    auto take = [&](size_t bytes) -> void* {
        void* p = ws + off;
        off = (off + bytes + 255) & ~(size_t)255;
        return p;
    };

    float*  dis    = (float*)take((size_t)N * 4);
    float2* A      = (float2*)take((size_t)N * 8);
    float2* B      = (float2*)take((size_t)N * 8);
    float2* C      = (float2*)take((size_t)N * 8);
    float2* outacc = (float2*)take((size_t)N * 8);
    float*  U      = (float*)take((size_t)N * 4);
    float*  part   = (float*)take(8192 * 4);
    float*  scal   = (float*)take(64 * 4);
    int*    TU     = (int*)take((size_t)(n2 + 1) * 4);
    int*    bsum   = (int*)take(1024 * 4);
    int*    boff   = (int*)take(1025 * 4);
    int2*   rec    = (int2*)take((size_t)2 * E * 8);
    size_t  base   = off;

    // Partials region (pdeg then pprop reuse it); runtime-sized M.
    long long avail = (long long)ws_size - (long long)base;
    int M = 0;
    if (avail > 0) {
        long long mm = avail / ((long long)Npad * 8);
        M = (int)(mm > 16 ? 16 : mm);
    }
    const bool bucket_ok = (N <= (1 << 21)) && (nblk <= 1024) && (M >= 1);

    const int eb = (E + THREADS - 1) / THREADS;
    const int nb = (N + THREADS - 1) / THREADS;

    if (bucket_ok) {
        float2* pprop = (float2*)(ws + base);
        float*  pdeg  = (float*)(ws + base);

        hist_kernel<<<SB, THREADS, 2 * NB * 4, stream>>>(row, col, TU, E, NB, chunk);
        scan1_kernel<<<nblk, 256, 0, stream>>>(TU, bsum, n2);
        scan2_kernel<<<1, 1024, 0, stream>>>(bsum, boff, nblk);
        scan3_kernel<<<(n2 + 256) / 256, 256, 0, stream>>>(TU, boff, n2, nblk);
        scatter_kernel<<<SB, THREADS, 2 * NB * 4, stream>>>(row, col, ew, TU, rec, E, NB, chunk);
        degred_kernel<<<NB * M, THREADS, 0, stream>>>(rec, TU, pdeg, M);
        init_kernel<<<nb, THREADS, 0, stream>>>(x, pdeg, dis, A, outacc, Wc, N, M);

        // k = 1
        gather_kernel<<<NB * M, THREADS, 0, stream>>>(rec, TU, dis, A, pprop, N, NB, M);
        cheb_kernel<<<nb, THREADS, 0, stream>>>(pprop, (const float2*)nullptr, B, outacc, Wc, 1, N, M);
        float2 *t0 = A, *t1 = B, *fr = C;
        for (int k = 2; k < K; ++k) {
            gather_kernel<<<NB * M, THREADS, 0, stream>>>(rec, TU, dis, t1, pprop, N, NB, M);
            cheb_kernel<<<nb, THREADS, 0, stream>>>(pprop, t0, fr, outacc, Wc, k, N, M);
            float2* n0 = t1; float2* n1 = fr; float2* nf = t0;
            t0 = n0; t1 = n1; fr = nf;
        }
    } else {
        // ---- full-atomic fallback ----
        zero_kernel<<<nb, THREADS, 0, stream>>>(dis, N);
        deg_at_kernel<<<eb, THREADS, 0, stream>>>(row, col, ew, dis, E);
        init_at_kernel<<<nb, THREADS, 0, stream>>>(x, dis, A, outacc, Wc, N);
        zerof2_kernel<<<nb, THREADS, 0, stream>>>(B, N);
        prop_kernel<<<eb, THREADS, 0, stream>>>(row, col, ew, dis, A, B, E);
        cheb_at_kernel<<<nb, THREADS, 0, stream>>>(B, (const float2*)nullptr, outacc, Wc, 1, N);
        float2 *t0 = A, *t1 = B, *fr = C;
        for (int k = 2; k < K; ++k) {
            zerof2_kernel<<<nb, THREADS, 0, stream>>>(fr, N);
            prop_kernel<<<eb, THREADS, 0, stream>>>(row, col, ew, dis, t1, fr, E);
            cheb_at_kernel<<<nb, THREADS, 0, stream>>>(fr, t0, outacc, Wc, k, N);
            float2* n0 = t1; float2* n1 = fr; float2* nf = t0;
            t0 = n0; t1 = n1; fr = nf;
        }
    }

    u_max_kernel<<<nb, THREADS, 0, stream>>>(x, outacc, cb, W, b, U, part, N);
    reduce_max_kernel<<<1, 1024, 0, stream>>>(part, nb, scal);
    exp_sum_kernel<<<nb, THREADS, 0, stream>>>(U, scal, part, N);
    reduce_sum_kernel<<<1, 1024, 0, stream>>>(part, nb, scal + 1);
    scale_kernel<<<nb, THREADS, 0, stream>>>(U, scal + 1, out, N);
}

// Round 8
// 462.386 us; speedup vs baseline: 6.2473x; 1.1102x over previous
//
#include <hip/hip_runtime.h>
#include <math.h>

#define THREADS 256
#define SB 1024           // blocks for hist/scatter passes (chunked edge ranges)
#define BSH 10            // bucket shift: 1024 nodes per bucket
#define BSZ 1024
#define BMSK 1023
#define SEG 2048          // edges per scatter segment (<= 8 * THREADS)

// ---------------------------------------------------------------------------
// Per-block LDS histograms over node buckets (bucket = 1024 nodes).
// TU[k*SB+b]       = #edges in block b's chunk with row-bucket k (self excl.)
// TU[(NB+k)*SB+b]  = same for col-bucket.
__global__ void hist_kernel(const int* __restrict__ row, const int* __restrict__ col,
                            int* __restrict__ TU, int E, int NB, int chunk) {
    extern __shared__ int sh[];
    int t = threadIdx.x, b = blockIdx.x;
    for (int k = t; k < 2 * NB; k += THREADS) sh[k] = 0;
    __syncthreads();
    int lo = b * chunk;
    int hi = min(lo + chunk, E);
    for (int e = lo + t; e < hi; e += THREADS) {
        int r = row[e], c = col[e];
        if (r != c) {
            atomicAdd(&sh[r >> BSH], 1);
            atomicAdd(&sh[NB + (c >> BSH)], 1);
        }
    }
    __syncthreads();
    for (int k = t; k < 2 * NB; k += THREADS) TU[k * SB + b] = sh[k];
}

// ---------------------------------------------------------------------------
// Exclusive scan over n elements, in place. scan2 handles <=1024 chunks.
__global__ void scan1_kernel(int* __restrict__ data, int* __restrict__ bsum, int n) {
    __shared__ int s[256];
    int t = threadIdx.x;
    int i = blockIdx.x * 256 + t;
    int v = (i < n) ? data[i] : 0;
    s[t] = v;
    __syncthreads();
    for (int d = 1; d < 256; d <<= 1) {
        int xv = (t >= d) ? s[t - d] : 0;
        __syncthreads();
        s[t] += xv;
        __syncthreads();
    }
    if (i < n) data[i] = s[t] - v;               // block-local exclusive
    if (t == 255) bsum[blockIdx.x] = s[255];
}

__global__ void scan2_kernel(const int* __restrict__ bsum, int* __restrict__ boff, int nb) {
    __shared__ int s[1024];
    int t = threadIdx.x;
    int v = (t < nb) ? bsum[t] : 0;
    s[t] = v;
    __syncthreads();
    for (int d = 1; d < 1024; d <<= 1) {
        int xv = (t >= d) ? s[t - d] : 0;
        __syncthreads();
        s[t] += xv;
        __syncthreads();
    }
    if (t < nb) boff[t] = s[t] - v;
    if (t == nb - 1) boff[nb] = s[t];            // grand total
}

__global__ void scan3_kernel(int* __restrict__ data, const int* __restrict__ boff,
                             int n, int nbk) {
    int i = blockIdx.x * blockDim.x + threadIdx.x;
    if (i < n) data[i] += boff[i >> 8];
    else if (i == n) data[n] = boff[nbk];        // append grand total
}

// ---------------------------------------------------------------------------
// Scatter with segment-local counting sort: per 2048-edge segment, records are
// bucket-ordered in LDS staging, then written out by a cooperative linear
// sweep (consecutive lanes -> consecutive addresses -> full-line writes).
// Per-block global ranges from TU are disjoint -> no global atomics.
__global__ void scatter_kernel(const int* __restrict__ row, const int* __restrict__ col,
                               const float* __restrict__ ew,
                               const int* __restrict__ TU, int2* __restrict__ rec,
                               int E, int NB, int chunk) {
    extern __shared__ int sh[];
    const int nb2 = 2 * NB;                       // <= 256 (guarded on host)
    int* cur   = sh;                              // [nb2]  block-local global bases
    int* sbase = sh + nb2;                        // [nb2]  segment staging bases
    int* scur  = sh + 2 * nb2;                    // [nb2]  segment placement cursors
    int* stmp  = sh + 3 * nb2;                    // [256]  scan temp
    int  basei = (3 * nb2 + 256 + 1) & ~1;        // even int offset
    unsigned char* bid = (unsigned char*)(sh + basei);        // [2*SEG] bucket ids
    int2* staged = (int2*)(sh + basei + (2 * SEG) / 4);       // [2*SEG] records

    int t = threadIdx.x, b = blockIdx.x;
    for (int k = t; k < nb2; k += THREADS) cur[k] = TU[k * SB + b];
    int lo = b * chunk;
    int hi = min(lo + chunk, E);

    for (int slo = lo; slo < hi; slo += SEG) {
        int scount = min(SEG, hi - slo);
        for (int k = t; k < nb2; k += THREADS) sbase[k] = 0;
        __syncthreads();

        // load up to 8 edges/thread into registers, count buckets in LDS
        int er[8], ec[8];
        float ewv[8];
#pragma unroll
        for (int j = 0; j < 8; ++j) {
            er[j] = -1;
            int e = slo + j * THREADS + t;
            if (e < slo + scount) {
                int r = row[e], c = col[e];
                if (r != c) {
                    er[j] = r; ec[j] = c; ewv[j] = ew[e];
                    atomicAdd(&sbase[r >> BSH], 1);
                    atomicAdd(&sbase[NB + (c >> BSH)], 1);
                }
            }
        }
        __syncthreads();

        // exclusive scan of per-bucket counts (nb2 <= 256)
        int v = (t < nb2) ? sbase[t] : 0;
        stmp[t] = v;
        __syncthreads();
        for (int d = 1; d < 256; d <<= 1) {
            int xv = (t >= d) ? stmp[t - d] : 0;
            __syncthreads();
            stmp[t] += xv;
            __syncthreads();
        }
        if (t < nb2) { sbase[t] = stmp[t] - v; scur[t] = stmp[t] - v; }
        int total = stmp[255];
        __syncthreads();

        // ranked placement into bucket-ordered staging
#pragma unroll
        for (int j = 0; j < 8; ++j) {
            if (er[j] >= 0) {
                int r = er[j], c = ec[j];
                int wbits = __float_as_int(ewv[j]);
                int k1 = r >> BSH;
                int p1 = atomicAdd(&scur[k1], 1);
                staged[p1] = make_int2(r & BMSK, wbits);
                bid[p1] = (unsigned char)k1;
                int k2 = NB + (c >> BSH);
                int p2 = atomicAdd(&scur[k2], 1);
                staged[p2] = make_int2((r << BSH) | (c & BMSK), wbits);
                bid[p2] = (unsigned char)k2;
            }
        }
        __syncthreads();

        // cooperative dense write-out
        for (int j = t; j < total; j += THREADS) {
            int k = bid[j];
            rec[cur[k] + (j - sbase[k])] = staged[j];
        }
        __syncthreads();

        // advance block cursors
        for (int k = t; k < nb2; k += THREADS) cur[k] += scur[k] - sbase[k];
        __syncthreads();
    }
}

// ---------------------------------------------------------------------------
// deg partials: grid = NB*M sub-blocks; LDS accumulate a record slice, plain
// writes to pdeg[(bk*M+m)*BSZ + local].
__global__ void degred_kernel(const int2* __restrict__ rec, const int* __restrict__ TU,
                              float* __restrict__ pdeg, int M) {
    __shared__ float acc[BSZ];
    int t = threadIdx.x;
    int bk = blockIdx.x / M, m = blockIdx.x % M;
    for (int j = t; j < BSZ; j += THREADS) acc[j] = 0.f;
    __syncthreads();
    int s = TU[bk * SB];
    int e2 = TU[(bk + 1) * SB];
    int len = e2 - s;
    int lo = s + (int)((long long)len * m / M);
    int hi = s + (int)((long long)len * (m + 1) / M);
    for (int i = lo + t; i < hi; i += THREADS) {
        int2 p = rec[i];
        atomicAdd(&acc[p.x], __int_as_float(p.y));
    }
    __syncthreads();
    float* dst = pdeg + (size_t)(bk * M + m) * BSZ;
    for (int j = t; j < BSZ; j += THREADS) dst[j] = acc[j];
}

// ---------------------------------------------------------------------------
// init (fused deg-partial reduce): dis = rsqrt(sum pdeg); Tx0 = x[:, :2];
// outacc = Tx0 @ Wc[0].
__global__ void init_kernel(const float* __restrict__ x, const float* __restrict__ pdeg,
                            float* __restrict__ dis, float2* __restrict__ tx0,
                            float2* __restrict__ outacc, const float* __restrict__ Wc,
                            int N, int M) {
    int i = blockIdx.x * blockDim.x + threadIdx.x;
    if (i >= N) return;
    int bk = i >> BSH, li = i & BMSK;
    const float* src = pdeg + (size_t)bk * M * BSZ + li;
    float d = 0.f;
    for (int m = 0; m < M; ++m) d += src[(size_t)m * BSZ];
    dis[i] = (d > 0.f) ? rsqrtf(d) : 0.f;
    float x0 = x[3 * i + 0];
    float x1 = x[3 * i + 1];
    tx0[i] = make_float2(x0, x1);
    outacc[i] = make_float2(x0 * Wc[0] + x1 * Wc[2],
                            x0 * Wc[1] + x1 * Wc[3]);
}

// ---------------------------------------------------------------------------
// Propagation partials: grid = NB*M; LDS accumulate norm*h over a col-record
// slice; plain float2 writes. Separate sax/say arrays -> all 32 LDS banks.
__global__ void gather_kernel(const int2* __restrict__ rec, const int* __restrict__ TU,
                              const float* __restrict__ dis, const float2* __restrict__ h,
                              float2* __restrict__ pprop, int N, int NB, int M) {
    __shared__ float sax[BSZ], say[BSZ], sdis[BSZ];
    int t = threadIdx.x;
    int bk = blockIdx.x / M, m = blockIdx.x % M;
    for (int j = t; j < BSZ; j += THREADS) {
        sax[j] = 0.f;
        say[j] = 0.f;
        int node = (bk << BSH) + j;
        sdis[j] = (node < N) ? dis[node] : 0.f;
    }
    __syncthreads();
    int s = TU[(NB + bk) * SB];
    int e2 = TU[(NB + bk + 1) * SB];
    int len = e2 - s;
    int lo = s + (int)((long long)len * m / M);
    int hi = s + (int)((long long)len * (m + 1) / M);
    for (int i = lo + t; i < hi; i += THREADS) {
        int2 p = rec[i];
        int r  = ((unsigned)p.x) >> BSH;
        int cl = p.x & BMSK;
        float w = -dis[r] * __int_as_float(p.y) * sdis[cl];
        float2 hv = h[r];
        atomicAdd(&sax[cl], w * hv.x);
        atomicAdd(&say[cl], w * hv.y);
    }
    __syncthreads();
    float2* dst = pprop + (size_t)(bk * M + m) * BSZ;
    for (int j = t; j < BSZ; j += THREADS) dst[j] = make_float2(sax[j], say[j]);
}

// ---------------------------------------------------------------------------
// Chebyshev node step (fused partial reduce): v = sum_m pprop;
// v = 2v - tx0 (if k>=2); txk = v; outacc += v @ Wc[k].
__global__ void cheb_kernel(const float2* __restrict__ pprop, const float2* __restrict__ tx0,
                            float2* __restrict__ txk, float2* __restrict__ outacc,
                            const float* __restrict__ Wc, int k, int N, int M) {
    int i = blockIdx.x * blockDim.x + threadIdx.x;
    if (i >= N) return;
    int bk = i >> BSH, li = i & BMSK;
    const float2* src = pprop + (size_t)bk * M * BSZ + li;
    float2 v = make_float2(0.f, 0.f);
    for (int m = 0; m < M; ++m) {
        float2 p = src[(size_t)m * BSZ];
        v.x += p.x;
        v.y += p.y;
    }
    if (tx0) {
        float2 tv = tx0[i];
        v.x = 2.f * v.x - tv.x;
        v.y = 2.f * v.y - tv.y;
    }
    txk[i] = v;
    float2 o = outacc[i];
    o.x += v.x * Wc[4 * k + 0] + v.y * Wc[4 * k + 2];
    o.y += v.x * Wc[4 * k + 1] + v.y * Wc[4 * k + 3];
    outacc[i] = o;
}

// ---------------------------------------------------------------------------
// Full-atomic fallback kernels (only if workspace is too small).
__global__ void zero_kernel(float* __restrict__ p, int n) {
    int i = blockIdx.x * blockDim.x + threadIdx.x;
    if (i < n) p[i] = 0.f;
}
__global__ void zerof2_kernel(float2* __restrict__ p, int n) {
    int i = blockIdx.x * blockDim.x + threadIdx.x;
    if (i < n) p[i] = make_float2(0.f, 0.f);
}
__global__ void deg_at_kernel(const int* __restrict__ row, const int* __restrict__ col,
                              const float* __restrict__ ew, float* __restrict__ deg, int E) {
    int e = blockIdx.x * blockDim.x + threadIdx.x;
    if (e >= E) return;
    int r = row[e], c = col[e];
    if (r != c) atomicAdd(&deg[r], ew[e]);
}
__global__ void init_at_kernel(const float* __restrict__ x, float* __restrict__ deg,
                               float2* __restrict__ tx0, float2* __restrict__ outacc,
                               const float* __restrict__ Wc, int N) {
    int i = blockIdx.x * blockDim.x + threadIdx.x;
    if (i >= N) return;
    float d = deg[i];
    deg[i] = (d > 0.f) ? rsqrtf(d) : 0.f;
    float x0 = x[3 * i + 0];
    float x1 = x[3 * i + 1];
    tx0[i] = make_float2(x0, x1);
    outacc[i] = make_float2(x0 * Wc[0] + x1 * Wc[2],
                            x0 * Wc[1] + x1 * Wc[3]);
}
__global__ void prop_kernel(const int* __restrict__ row, const int* __restrict__ col,
                            const float* __restrict__ ew, const float* __restrict__ dis,
                            const float2* __restrict__ h, float2* __restrict__ o, int E) {
    int e = blockIdx.x * blockDim.x + threadIdx.x;
    if (e >= E) return;
    int r = row[e], c = col[e];
    if (r == c) return;
    float w = -dis[r] * ew[e] * dis[c];
    if (w == 0.f) return;
    float2 hv = h[r];
    atomicAdd(&o[c].x, w * hv.x);
    atomicAdd(&o[c].y, w * hv.y);
}
__global__ void cheb_at_kernel(float2* __restrict__ raw, const float2* __restrict__ tx0,
                               float2* __restrict__ outacc, const float* __restrict__ Wc,
                               int k, int N) {
    int i = blockIdx.x * blockDim.x + threadIdx.x;
    if (i >= N) return;
    float2 v = raw[i];
    if (tx0) {
        float2 t = tx0[i];
        v.x = 2.f * v.x - t.x;
        v.y = 2.f * v.y - t.y;
        raw[i] = v;
    }
    float2 o = outacc[i];
    o.x += v.x * Wc[4 * k + 0] + v.y * Wc[4 * k + 2];
    o.y += v.x * Wc[4 * k + 1] + v.y * Wc[4 * k + 3];
    outacc[i] = o;
}

// ---------------------------------------------------------------------------
// Fused epilogue (3 kernels): per-block (max, sum-of-exp) via LSE rescale.
__global__ void u_ms_kernel(const float* __restrict__ x, const float2* __restrict__ outacc,
                            const float* __restrict__ cb, const float* __restrict__ W,
                            const float* __restrict__ b, float* __restrict__ U,
                            float* __restrict__ part2, int N) {
    __shared__ float sm[THREADS / 64];
    __shared__ float bmax;
    int i = blockIdx.x * blockDim.x + threadIdx.x;
    int t = threadIdx.x;
    float u = -INFINITY;
    if (i < N) {
        float2 o = outacc[i];
        float h0 = fmaxf(o.x + cb[0], 0.f);
        float h1 = fmaxf(o.y + cb[1], 0.f);
        u = x[3 * i + 2] * W[0] + h0 * W[1] + h1 * W[2] + b[0];
        U[i] = u;
    }
    float mv = u;
    for (int off = 32; off > 0; off >>= 1) mv = fmaxf(mv, __shfl_down(mv, off));
    if ((t & 63) == 0) sm[t >> 6] = mv;
    __syncthreads();
    if (t == 0) {
        float m = sm[0];
        for (int w = 1; w < THREADS / 64; ++w) m = fmaxf(m, sm[w]);
        bmax = m;
    }
    __syncthreads();
    float bm = bmax;
    float e = (i < N) ? expf(u - bm) : 0.f;
    for (int off = 32; off > 0; off >>= 1) e += __shfl_down(e, off);
    __syncthreads();
    if ((t & 63) == 0) sm[t >> 6] = e;
    __syncthreads();
    if (t == 0) {
        float s = sm[0];
        for (int w = 1; w < THREADS / 64; ++w) s += sm[w];
        part2[2 * blockIdx.x]     = bm;
        part2[2 * blockIdx.x + 1] = s;
    }
}

__global__ void red_ms_kernel(const float* __restrict__ part2, int n,
                              float* __restrict__ scal) {
    __shared__ float sm[16];
    __shared__ float gmax;
    int t = threadIdx.x;
    float m = -INFINITY;
    for (int i = t; i < n; i += blockDim.x) m = fmaxf(m, part2[2 * i]);
    for (int off = 32; off > 0; off >>= 1) m = fmaxf(m, __shfl_down(m, off));
    int wid = t >> 6;
    if ((t & 63) == 0) sm[wid] = m;
    __syncthreads();
    if (t == 0) {
        float r = sm[0];
        int nw = blockDim.x >> 6;
        for (int w = 1; w < nw; ++w) r = fmaxf(r, sm[w]);
        gmax = r;
    }
    __syncthreads();
    float M = gmax;
    float s = 0.f;
    for (int i = t; i < n; i += blockDim.x) s += part2[2 * i + 1] * expf(part2[2 * i] - M);
    for (int off = 32; off > 0; off >>= 1) s += __shfl_down(s, off);
    __syncthreads();
    if ((t & 63) == 0) sm[wid] = s;
    __syncthreads();
    if (t == 0) {
        float r = sm[0];
        int nw = blockDim.x >> 6;
        for (int w = 1; w < nw; ++w) r += sm[w];
        scal[0] = M;
        scal[1] = 1.f / r;
    }
}

__global__ void out_kernel(const float* __restrict__ U, const float* __restrict__ scal,
                           float* __restrict__ out, int N) {
    int i = blockIdx.x * blockDim.x + threadIdx.x;
    if (i < N) out[i] = expf(U[i] - scal[0]) * scal[1];
}

// ---------------------------------------------------------------------------
extern "C" void kernel_launch(void* const* d_in, const int* in_sizes, int n_in,
                              void* d_out, int out_size, void* d_ws, size_t ws_size,
                              hipStream_t stream) {
    (void)n_in; (void)out_size;
    const float* x    = (const float*)d_in[0];
    const int*   eidx = (const int*)d_in[1];     // int32 per harness contract
    const float* ew   = (const float*)d_in[2];
    const float* Wc   = (const float*)d_in[3];
    const float* cb   = (const float*)d_in[4];
    const float* W    = (const float*)d_in[5];
    const float* b    = (const float*)d_in[6];
    float*       out  = (float*)d_out;

    const int N = in_sizes[0] / 3;
    const int E = in_sizes[2];
    const int K = in_sizes[3] / 4;
    const int* row = eidx;
    const int* col = eidx + E;

    const int NB    = (N + BMSK) >> BSH;         // 1024-node buckets
    const int nb2   = 2 * NB;
    const int n2    = nb2 * SB;                  // unified count-table length
    const int nblk  = (n2 + 255) / 256;
    const int chunk = (E + SB - 1) / SB;
    const int Npad  = NB << BSH;

    char* ws = (char*)d_ws;
    size_t off = 0;
    auto take = [&](size_t bytes) -> void* {
        void* p = ws + off;
        off = (off + bytes + 255) & ~(size_t)255;
        return p;
    };

    float*  dis    = (float*)take((size_t)N * 4);
    float2* A      = (float2*)take((size_t)N * 8);
    float2* B      = (float2*)take((size_t)N * 8);
    float2* C      = (float2*)take((size_t)N * 8);
    float2* outacc = (float2*)take((size_t)N * 8);
    float*  U      = (float*)take((size_t)N * 4);
    float*  part   = (float*)take(8192 * 4);
    float*  scal   = (float*)take(64 * 4);
    int*    TU     = (int*)take((size_t)(n2 + 1) * 4);
    int*    bsum   = (int*)take(1024 * 4);
    int*    boff   = (int*)take(1025 * 4);
    int2*   rec    = (int2*)take((size_t)2 * E * 8);
    size_t  base   = off;

    // Partials region (pdeg then pprop reuse it); runtime-sized M.
    long long avail = (long long)ws_size - (long long)base;
    int M = 0;
    if (avail > 0) {
        long long mm = avail / ((long long)Npad * 8);
        M = (int)(mm > 16 ? 16 : mm);
    }
    const bool bucket_ok = (nb2 <= 256) && (nblk <= 1024) && (M >= 1);

    const int eb = (E + THREADS - 1) / THREADS;
    const int nb = (N + THREADS - 1) / THREADS;

    if (bucket_ok) {
        float2* pprop = (float2*)(ws + base);
        float*  pdeg  = (float*)(ws + base);

        // dynamic LDS for scatter (must match device-side layout)
        int basei = (3 * nb2 + 256 + 1) & ~1;
        size_t scat_lds = (size_t)(basei + (2 * SEG) / 4 + 4 * SEG) * 4;

        hist_kernel<<<SB, THREADS, nb2 * 4, stream>>>(row, col, TU, E, NB, chunk);
        scan1_kernel<<<nblk, 256, 0, stream>>>(TU, bsum, n2);
        scan2_kernel<<<1, 1024, 0, stream>>>(bsum, boff, nblk);
        scan3_kernel<<<(n2 + 256) / 256, 256, 0, stream>>>(TU, boff, n2, nblk);
        scatter_kernel<<<SB, THREADS, scat_lds, stream>>>(row, col, ew, TU, rec, E, NB, chunk);
        degred_kernel<<<NB * M, THREADS, 0, stream>>>(rec, TU, pdeg, M);
        init_kernel<<<nb, THREADS, 0, stream>>>(x, pdeg, dis, A, outacc, Wc, N, M);

        // k = 1
        gather_kernel<<<NB * M, THREADS, 0, stream>>>(rec, TU, dis, A, pprop, N, NB, M);
        cheb_kernel<<<nb, THREADS, 0, stream>>>(pprop, (const float2*)nullptr, B, outacc, Wc, 1, N, M);
        float2 *t0 = A, *t1 = B, *fr = C;
        for (int k = 2; k < K; ++k) {
            gather_kernel<<<NB * M, THREADS, 0, stream>>>(rec, TU, dis, t1, pprop, N, NB, M);
            cheb_kernel<<<nb, THREADS, 0, stream>>>(pprop, t0, fr, outacc, Wc, k, N, M);
            float2* n0 = t1; float2* n1 = fr; float2* nf = t0;
            t0 = n0; t1 = n1; fr = nf;
        }
    } else {
        // ---- full-atomic fallback ----
        zero_kernel<<<nb, THREADS, 0, stream>>>(dis, N);
        deg_at_kernel<<<eb, THREADS, 0, stream>>>(row, col, ew, dis, E);
        init_at_kernel<<<nb, THREADS, 0, stream>>>(x, dis, A, outacc, Wc, N);
        zerof2_kernel<<<nb, THREADS, 0, stream>>>(B, N);
        prop_kernel<<<eb, THREADS, 0, stream>>>(row, col, ew, dis, A, B, E);
        cheb_at_kernel<<<nb, THREADS, 0, stream>>>(B, (const float2*)nullptr, outacc, Wc, 1, N);
        float2 *t0 = A, *t1 = B, *fr = C;
        for (int k = 2; k < K; ++k) {
            zerof2_kernel<<<nb, THREADS, 0, stream>>>(fr, N);
            prop_kernel<<<eb, THREADS, 0, stream>>>(row, col, ew, dis, t1, fr, E);
            cheb_at_kernel<<<nb, THREADS, 0, stream>>>(fr, t0, outacc, Wc, k, N);
            float2* n0 = t1; float2* n1 = fr; float2* nf = t0;
            t0 = n0; t1 = n1; fr = nf;
        }
    }

    u_ms_kernel<<<nb, THREADS, 0, stream>>>(x, outacc, cb, W, b, U, part, N);
    red_ms_kernel<<<1, 1024, 0, stream>>>(part, nb, scal);
    out_kernel<<<nb, THREADS, 0, stream>>>(U, scal, out, N);
}